// Round 8
// baseline (868.457 us; speedup 1.0000x reference)
//
#include <hip/hip_runtime.h>
#include <math.h>

#define BB 4
#define LL 2048
#define DD 1024
#define HH 16
#define HD 64
#define BL (BB*LL)

typedef __attribute__((ext_vector_type(8))) short bf16x8;
typedef __attribute__((ext_vector_type(4))) short bf16x4;
typedef __attribute__((ext_vector_type(4))) float f32x4;

__device__ inline short f2bf(float f) {
    union { float f; unsigned u; } v; v.f = f;
    unsigned r = v.u + 0x7fffu + ((v.u >> 16) & 1u);   // RNE
    return (short)(r >> 16);
}

// pack two fp32 -> two bf16 (truncation; p>=0 so bias is benign, ~2^-9 rel)
__device__ inline unsigned pk_bf16(float a, float b) {
    union { float f; unsigned u; } x, y; x.f = a; y.f = b;
    return (x.u >> 16) | (y.u & 0xffff0000u);
}

__device__ inline float exp2x(float x) {
#if __has_builtin(__builtin_amdgcn_exp2f)
    return __builtin_amdgcn_exp2f(x);
#else
    return exp2f(x);
#endif
}

__device__ inline f32x4 mfma16x16x16_bf16(bf16x4 a, bf16x4 b, f32x4 c) {
#if __has_builtin(__builtin_amdgcn_mfma_f32_16x16x16bf16_1k)
    return __builtin_amdgcn_mfma_f32_16x16x16bf16_1k(a, b, c, 0, 0, 0);
#elif __has_builtin(__builtin_amdgcn_mfma_f32_16x16x16_bf16)
    return __builtin_amdgcn_mfma_f32_16x16x16_bf16(a, b, c, 0, 0, 0);
#else
    f32x4 d;
    asm volatile("v_mfma_f32_16x16x16_bf16 %0, %1, %2, %3"
                 : "=v"(d) : "v"(a), "v"(b), "v"(c));
    return d;
#endif
}

__device__ inline void gload_lds16(const void* g, void* l) {
    __builtin_amdgcn_global_load_lds(
        (const __attribute__((address_space(1))) unsigned int*)g,
        (__attribute__((address_space(3))) unsigned int*)l, 16, 0, 0);
}

// ---------------------------------------------------------------------------
// fp32 -> bf16 cast, 8 elem/thread.
// ---------------------------------------------------------------------------
__global__ __launch_bounds__(256) void cast_kernel(
    const float* __restrict__ in, short* __restrict__ out, int n)
{
    int i = (blockIdx.x * 256 + threadIdx.x) * 8;
    float4 a = *(const float4*)(in + i);
    float4 b = *(const float4*)(in + i + 4);
    bf16x8 o;
    o[0]=f2bf(a.x); o[1]=f2bf(a.y); o[2]=f2bf(a.z); o[3]=f2bf(a.w);
    o[4]=f2bf(b.x); o[5]=f2bf(b.y); o[6]=f2bf(b.z); o[7]=f2bf(b.w);
    *(bf16x8*)(out + i) = o;
}

// 4 weight matrices (contiguous dsts), one launch. grid = 4 * n_w/2048.
__global__ __launch_bounds__(256) void cast4_kernel(
    const float* __restrict__ w0, const float* __restrict__ w1,
    const float* __restrict__ w2, const float* __restrict__ w3,
    short* __restrict__ out)
{
    const int nw_blocks = (DD*DD) / 2048;
    int sel = blockIdx.x / nw_blocks;
    int blk = blockIdx.x % nw_blocks;
    const float* in = (sel == 0) ? w0 : (sel == 1) ? w1 : (sel == 2) ? w2 : w3;
    int i = (blk * 256 + threadIdx.x) * 8;
    float4 a = *(const float4*)(in + i);
    float4 b = *(const float4*)(in + i + 4);
    bf16x8 o;
    o[0]=f2bf(a.x); o[1]=f2bf(a.y); o[2]=f2bf(a.z); o[3]=f2bf(a.w);
    o[4]=f2bf(b.x); o[5]=f2bf(b.y); o[6]=f2bf(b.z); o[7]=f2bf(b.w);
    *(bf16x8*)(out + (size_t)sel * DD * DD + i) = o;
}

// ---------------------------------------------------------------------------
// RoPE table: tab[l*32 + f] = (cos, sin) of l * 10000^(-f/32), f=0..31.
// ---------------------------------------------------------------------------
__global__ __launch_bounds__(256) void rope_tab_kernel(float2* __restrict__ tab)
{
    int idx = blockIdx.x * 256 + threadIdx.x;
    int lq = idx >> 5, f = idx & 31;
    float inv = __expf((float)f * (-9.210340371976184f / 32.0f));
    float s, c;
    sincosf((float)lq * inv, &s, &c);
    tab[idx] = make_float2(c, s);
}

// ---------------------------------------------------------------------------
// Shared 128x128-tile bf16 MFMA K-loop (m97 structure).
// ---------------------------------------------------------------------------
__device__ inline void gemm_bt_128(const short* __restrict__ A,
                                   const short* __restrict__ B,
                                   short* Ash, short* Bsh,
                                   int i0, int n0, f32x4 (&acc)[4][4])
{
    const int t  = threadIdx.x;
    const int w  = t >> 6;
    const int l  = t & 63;
    const int g  = (t >> 4) & 3;
    const int ln = t & 15;
    const int rh = (w >> 1) * 64;
    const int ch = (w & 1) * 64;
    const int srow = w * 8 + (l >> 3);
    const int skol = (l & 7) * 8;

    for (int k0 = 0; k0 < DD; k0 += 64) {
        __syncthreads();
        const short* ga = A + (size_t)(i0 + srow) * DD + k0 + skol;
        const short* gb = B + (size_t)(n0 + srow) * DD + k0 + skol;
        short* la = Ash + w * 512;   // wave-uniform base
        short* lb = Bsh + w * 512;
        #pragma unroll
        for (int j = 0; j < 4; ++j) {
            gload_lds16(ga + j * 32 * DD, la + j * 2048);
            gload_lds16(gb + j * 32 * DD, lb + j * 2048);
        }
        __syncthreads();

        #pragma unroll
        for (int kk = 0; kk < 2; ++kk) {
            bf16x8 af[4], bfr[4];
            #pragma unroll
            for (int mi = 0; mi < 4; ++mi)
                af[mi] = *(const bf16x8*)(Ash + (rh + mi*16 + ln)*64 + kk*32 + 8*g);
            #pragma unroll
            for (int nj = 0; nj < 4; ++nj)
                bfr[nj] = *(const bf16x8*)(Bsh + (ch + nj*16 + ln)*64 + kk*32 + 8*g);
            #pragma unroll
            for (int mi = 0; mi < 4; ++mi)
                #pragma unroll
                for (int nj = 0; nj < 4; ++nj)
                    acc[mi][nj] = __builtin_amdgcn_mfma_f32_16x16x32_bf16(
                        af[mi], bfr[nj], acc[mi][nj], 0, 0, 0);
        }
    }
}

// ---------------------------------------------------------------------------
// Kernel 1: QKV projection + RoPE. 1-D grid 1536, XCD-aware decode (R7).
// ---------------------------------------------------------------------------
__global__ __launch_bounds__(256) void qkv_mfma_kernel(
    const short* __restrict__ xb, const short* __restrict__ Wqb,
    const short* __restrict__ Wkb, const short* __restrict__ Wvb,
    const float2* __restrict__ rope_tab,
    short* __restrict__ Qo, short* __restrict__ Ko, short* __restrict__ Vo)
{
    __shared__ short Ash[128*64];
    __shared__ short Bsh[128*64];

    const int gid = blockIdx.x;
    const int r8  = gid & 7;           // XCD slot (round-robin heuristic)
    const int u   = gid >> 3;          // 0..191
    const int i_idx = r8 * 8 + (u & 7);      // 0..63
    const int nz  = u >> 3;                  // 0..23
    const int n_idx = nz & 7;                // 0..7
    const int z   = nz >> 3;                 // 0..2

    const short* Wm = (z == 0) ? Wqb : ((z == 1) ? Wkb : Wvb);
    const int i0 = i_idx * 128;
    const int n0 = n_idx * 128;

    f32x4 acc[4][4];
    #pragma unroll
    for (int mi = 0; mi < 4; ++mi)
        #pragma unroll
        for (int nj = 0; nj < 4; ++nj) acc[mi][nj] = (f32x4){0.f,0.f,0.f,0.f};

    gemm_bt_128(xb, Wm, Ash, Bsh, i0, n0, acc);

    const int t  = threadIdx.x;
    const int w  = t >> 6;
    const int g  = (t >> 4) & 3;
    const int ln = t & 15;
    const int rh = (w >> 1) * 64;

    if (z == 2) {
        // two passes over heads; buf[64 d][136 seq-stride] spans Ash..Bsh.
        short* buf = Ash;
        const int b = i0 >> 11, l0 = i0 & (LL - 1);
        const int d = t >> 2;
        const int c = t & 3;
        #pragma unroll
        for (int hp = 0; hp < 2; ++hp) {
            __syncthreads();
            if ((w & 1) == hp) {
                #pragma unroll
                for (int nj = 0; nj < 4; ++nj)
                    #pragma unroll
                    for (int mi = 0; mi < 4; ++mi)
                        #pragma unroll
                        for (int r = 0; r < 4; ++r)
                            buf[(nj*16 + ln)*136 + rh + mi*16 + 4*g + r]
                                = f2bf(acc[mi][nj][r]);
            }
            __syncthreads();
            short* dst = Vo + ((size_t)((b*HH + n_idx*2 + hp)*HD + d)) * LL + l0;
            #pragma unroll
            for (int j = 0; j < 4; ++j)
                *(bf16x8*)(dst + c*8 + j*32) =
                    *(const bf16x8*)(buf + d*136 + c*8 + j*32);
        }
    } else {
        const int h = n_idx * 2 + (w & 1);
        short* Om = (z == 0) ? Qo : Ko;
        // Q: 1/sqrt(64) * log2(e) so scores feed exp2 directly
        const float sc = (z == 0) ? 0.180336880111112f : 1.0f;
        #pragma unroll
        for (int mi = 0; mi < 4; ++mi)
            #pragma unroll
            for (int r = 0; r < 4; ++r) {
                int i = i0 + rh + mi*16 + 4*g + r;
                int b = i >> 11, lq = i & (LL - 1);
                float2 cs0 = rope_tab[lq*32 + ln];        // freq ln
                float2 cs1 = rope_tab[lq*32 + ln + 16];   // freq ln+16
                float r0 = (acc[mi][0][r]*cs0.x - acc[mi][2][r]*cs0.y) * sc;
                float r2 = (acc[mi][2][r]*cs0.x + acc[mi][0][r]*cs0.y) * sc;
                float r1 = (acc[mi][1][r]*cs1.x - acc[mi][3][r]*cs1.y) * sc;
                float r3 = (acc[mi][3][r]*cs1.x + acc[mi][1][r]*cs1.y) * sc;
                size_t base = ((size_t)(b*HH + h) * LL + lq) * HD;
                Om[base + ln     ] = f2bf(r0);
                Om[base + ln + 16] = f2bf(r1);
                Om[base + ln + 32] = f2bf(r2);
                Om[base + ln + 48] = f2bf(r3);
            }
    }
}

// ---------------------------------------------------------------------------
// Kernel 2: bf16 MFMA flash attention, fully LDS-free (no __shared__, no
// barriers). grid = (B*H, L/64); bh on x keeps the XCD K/V locality.
// Each wave owns 16 queries (q = q0 + w*16 + ln).
//   S^T = K·Q^T  (K A-frags loaded DIRECT from global: wave's 2KB coalesced)
//   p = exp2(S') in C-layout regs; packed pf == B-operand layout of 16x16x16
//   O^T = V^T·P^T (V^T A-frags: per-lane contiguous 8B from (B,H,Hd,L))
// O^T C-layout: col = q = ln -> per-lane 1/l, contiguous bf16x4 stores.
// ---------------------------------------------------------------------------
__global__ __launch_bounds__(256) void attn_kernel(
    const short* __restrict__ Q, const short* __restrict__ K,
    const short* __restrict__ VT, short* __restrict__ AO)
{
    const int t  = threadIdx.x;
    const int w  = t >> 6;
    const int l  = t & 63;
    const int g  = l >> 4;
    const int ln = l & 15;

    const int bh = blockIdx.x;
    const int q0 = blockIdx.y * 64;
    const short* Qb  = Q  + ((size_t)bh * LL + q0 + w*16) * HD;
    const short* Kb  = K  + (size_t)bh * LL * HD;
    const short* VTb = VT + (size_t)bh * HD * LL;

    // Q B-frags: [n=q=ln][k=d=8g+j(+32)]
    bf16x8 qb0 = *(const bf16x8*)(Qb + (size_t)ln*HD + 8*g);
    bf16x8 qb1 = *(const bf16x8*)(Qb + (size_t)ln*HD + 32 + 8*g);

    f32x4 O[4];                    // O^T[db]: row d = db*16+4g+r, col q = ln
    #pragma unroll
    for (int db = 0; db < 4; ++db) O[db] = (f32x4){0.f,0.f,0.f,0.f};
    float l_acc = 0.f;

    const short* kfrag = Kb + (size_t)ln*HD + 8*g;          // + kt*HD + kb*1024
    const short* vfrag = VTb + (size_t)ln*LL + 4*g;         // + db*16*LL + kt + kb*16

    for (int kt = 0; kt < LL; kt += 64) {
        uint2 pf[4];
        #pragma unroll
        for (int kb = 0; kb < 4; ++kb) {
            // K A-frags direct from global: [m=key=kb*16+ln][k=d]
            const short* kp = kfrag + (size_t)(kt + kb*16)*HD;
            bf16x8 ka0 = *(const bf16x8*)(kp);
            bf16x8 ka1 = *(const bf16x8*)(kp + 32);
            f32x4 S = (f32x4){0.f,0.f,0.f,0.f};
            S = __builtin_amdgcn_mfma_f32_16x16x32_bf16(ka0, qb0, S, 0, 0, 0);
            S = __builtin_amdgcn_mfma_f32_16x16x32_bf16(ka1, qb1, S, 0, 0, 0);
            float p0 = exp2x(S[0]), p1 = exp2x(S[1]);
            float p2 = exp2x(S[2]), p3 = exp2x(S[3]);
            l_acc += (p0 + p1) + (p2 + p3);
            pf[kb].x = pk_bf16(p0, p1);
            pf[kb].y = pk_bf16(p2, p3);
        }

        // O^T += V^T-frag (A) x P^T-frag (B), 16x16x16
        #pragma unroll
        for (int kb = 0; kb < 4; ++kb) {
            bf16x4 pb = __builtin_bit_cast(bf16x4, pf[kb]);
            #pragma unroll
            for (int db = 0; db < 4; ++db) {
                bf16x4 vf = *(const bf16x4*)(vfrag + (size_t)(db*16)*LL + kt + kb*16);
                O[db] = mfma16x16x16_bf16(vf, pb, O[db]);
            }
        }
    }

    // epilogue: l over g-lanes; every lane then owns q = ln
    float lr = l_acc;
    lr += __shfl_xor(lr, 16);
    lr += __shfl_xor(lr, 32);
    float inv = 1.0f / lr;

    const int b = bh >> 4, h = bh & 15;
    const int q = q0 + w*16 + ln;
    short* dst = AO + ((size_t)(b*LL + q)) * DD + h*HD + 4*g;
    #pragma unroll
    for (int db = 0; db < 4; ++db) {
        bf16x4 o4;
        o4[0] = f2bf(O[db][0] * inv);
        o4[1] = f2bf(O[db][1] * inv);
        o4[2] = f2bf(O[db][2] * inv);
        o4[3] = f2bf(O[db][3] * inv);
        *(bf16x4*)(dst + db*16) = o4;
    }
}

// ---------------------------------------------------------------------------
// Kernel 3: output projection. 1-D grid 512, XCD-aware decode (R7).
// ---------------------------------------------------------------------------
__global__ __launch_bounds__(256) void oproj_mfma_kernel(
    const short* __restrict__ A, const short* __restrict__ Wob,
    float* __restrict__ out)
{
    __shared__ short Ash[128*64];
    __shared__ short Bsh[128*64];

    const int gid = blockIdx.x;
    const int r8  = gid & 7;
    const int u   = gid >> 3;              // 0..63
    const int i_idx = r8 * 8 + (u & 7);    // 0..63
    const int n_idx = u >> 3;              // 0..7
    const int i0 = i_idx * 128;
    const int n0 = n_idx * 128;

    f32x4 acc[4][4];
    #pragma unroll
    for (int mi = 0; mi < 4; ++mi)
        #pragma unroll
        for (int nj = 0; nj < 4; ++nj) acc[mi][nj] = (f32x4){0.f,0.f,0.f,0.f};

    gemm_bt_128(A, Wob, Ash, Bsh, i0, n0, acc);

    const int t  = threadIdx.x;
    const int w  = t >> 6;
    const int g  = (t >> 4) & 3;
    const int ln = t & 15;
    const int rh = (w >> 1) * 64;
    const int ch = (w & 1) * 64;

    #pragma unroll
    for (int mi = 0; mi < 4; ++mi)
        #pragma unroll
        for (int r = 0; r < 4; ++r) {
            size_t base = (size_t)(i0 + rh + mi*16 + 4*g + r) * DD + n0 + ch;
            #pragma unroll
            for (int nj = 0; nj < 4; ++nj)
                out[base + nj*16 + ln] = acc[mi][nj][r];
        }
}

// ---------------------------------------------------------------------------
extern "C" void kernel_launch(void* const* d_in, const int* in_sizes, int n_in,
                              void* d_out, int out_size, void* d_ws, size_t ws_size,
                              hipStream_t stream) {
    const float* x  = (const float*)d_in[0];
    const float* Wq = (const float*)d_in[1];
    const float* Wk = (const float*)d_in[2];
    const float* Wv = (const float*)d_in[3];
    const float* Wo = (const float*)d_in[4];
    float* out = (float*)d_out;

    const size_t n_x = (size_t)BL * DD;   // 8.4M
    const size_t n_w = (size_t)DD * DD;   // 1.05M
    short* xb  = (short*)d_ws;
    short* Wqb = xb  + n_x;               // Wqb..Wob contiguous (cast4 relies on it)
    short* Wkb = Wqb + n_w;
    short* Wvb = Wkb + n_w;
    short* Wob = Wvb + n_w;
    short* Q   = Wob + n_w;
    short* K   = Q   + n_x;
    short* VTg = K   + n_x;               // V transposed: (B,H,Hd,L)
    short* AOb = VTg + n_x;
    float2* tab = (float2*)(AOb + n_x);   // 65536 float2 = 512 KB

    rope_tab_kernel<<<256, 256, 0, stream>>>(tab);
    cast_kernel<<<n_x/2048, 256, 0, stream>>>(x, xb, (int)n_x);
    cast4_kernel<<<4*(n_w/2048), 256, 0, stream>>>(Wq, Wk, Wv, Wo, Wqb);

    qkv_mfma_kernel<<<1536, 256, 0, stream>>>(xb, Wqb, Wkb, Wvb, tab, Q, K, VTg);

    dim3 g2(BB*HH, LL/64);
    attn_kernel<<<g2, 256, 0, stream>>>(Q, K, VTg, AOb);

    oproj_mfma_kernel<<<512, 256, 0, stream>>>(AOb, Wob, out);
}